// Round 9
// baseline (207.599 us; speedup 1.0000x reference)
//
#include <hip/hip_runtime.h>

#define INDIM 128
#define HIDD 64
#define BSHIFT 6                 // 64 nodes per bucket
#define BNODES 64
#define BCAP 4096                // per-bucket capacity (mean fill ~2112)
#define MAXBUCK 2048             // bucket-array capacity (N<=131072)
#define CHUNK 16384              // edges per block in pass A (202 blocks)
#define ATHREADS 512
#define BPT (MAXBUCK / ATHREADS) // 4
#define FB_THREADS 512
#define FB_WAVES (FB_THREADS / 64)

typedef float f32x2 __attribute__((ext_vector_type(2)));
using short8 = __attribute__((ext_vector_type(8))) short;   // 8 bf16 (4 VGPRs)
using f32x4  = __attribute__((ext_vector_type(4))) float;   // MFMA acc

__device__ inline unsigned short f2bf(float f) {   // RNE f32->bf16
    unsigned u = __float_as_uint(f);
    return (unsigned short)((u + 0x7fff + ((u >> 16) & 1)) >> 16);
}
__device__ inline float bflo(unsigned v) { return __uint_as_float(v << 16); }
__device__ inline unsigned cvtpk(float a, float b) {  // {bf16(a), bf16(b)<<16} RNE
    unsigned r;
    asm("v_cvt_pk_bf16_f32 %0, %1, %2" : "=v"(r) : "v"(a), "v"(b));
    return r;
}

// ---------------- CSR build ----------------

// Pass A: per-block LDS counting sort of CHUNK edges by destination bucket.
// Round-9 rework: NO dLds cache (re-read dstA from global -- streaming in
// phase 3, scattered-but-L1/L2-hot in phase 4); CHUNK doubled to 16384.
// LDS 88->52 KB => 3 blocks/CU (was 1) for latency hiding, and per-bucket
// write runs double (~10 entries => ~40B granules, less write amplification).
// NO nontemporal hints: phase 4 reads srcA/dstA scattered and NEEDS caching
// (round-7 lesson: nt there = 2.7x HBM over-fetch).
__global__ __launch_bounds__(ATHREADS, 4) void k_bucketA(
        const int* __restrict__ srcA, const int* __restrict__ dstA,
        int* __restrict__ bcnt, unsigned* __restrict__ bucketBuf,
        int E, int N, int NBUCK) {
    __shared__ int cnt[MAXBUCK];              // 8 KB
    __shared__ int cur[MAXBUCK];              // 8 KB
    __shared__ unsigned short gbase[MAXBUCK]; // 4 KB
    __shared__ unsigned short stage[CHUNK];   // 32 KB (local edge offsets)
    __shared__ int wsum[ATHREADS / 64];
    int t = threadIdx.x;
    int EV = E + N;
    int begin = blockIdx.x * CHUNK;
    int end = begin + CHUNK;
    if (end > EV) end = EV;
    if (begin >= EV) return;
    int nLoc = end - begin;

    for (int b = t; b < MAXBUCK; b += ATHREADS) cnt[b] = 0;
    __syncthreads();

    // phase 1: streaming read of dstA; LDS histogram of bucket ids
    for (int i = begin + t; i < end; i += ATHREADS) {
        int d = (i < E) ? dstA[i] : (i - E);
        atomicAdd(&cnt[d >> BSHIFT], 1);
    }
    __syncthreads();

    // phase 2a: exclusive scan of cnt via wave shuffles
    int vq[BPT];
    int psum = 0;
#pragma unroll
    for (int q = 0; q < BPT; ++q) { vq[q] = cnt[t * BPT + q]; psum += vq[q]; }
    int lane = t & 63, w = t >> 6;
    int s = psum;
#pragma unroll
    for (int off = 1; off < 64; off <<= 1) {
        int u = __shfl_up(s, off, 64);
        if (lane >= off) s += u;
    }
    if (lane == 63) wsum[w] = s;
    __syncthreads();
    if (t < ATHREADS / 64) {
        int x = wsum[t];
#pragma unroll
        for (int off = 1; off < ATHREADS / 64; off <<= 1) {
            int u = __shfl_up(x, off, 64);
            if (t >= off) x += u;
        }
        wsum[t] = x;   // inclusive wave sums
    }
    __syncthreads();
    int run = ((w > 0) ? wsum[w - 1] : 0) + s - psum;
#pragma unroll
    for (int q = 0; q < BPT; ++q) {
        cur[t * BPT + q] = run;
        run += vq[q];
    }

    // phase 2b: reserve global runs (staggered sweep start per block)
    int b0 = (int)(((unsigned)blockIdx.x * 683u) % (unsigned)NBUCK);
    for (int idx = t; idx < NBUCK; idx += ATHREADS) {
        int b = idx + b0;
        if (b >= NBUCK) b -= NBUCK;
        int c = cnt[b];
        gbase[b] = (unsigned short)((c > 0) ? atomicAdd(&bcnt[b], c) : 0);
    }
    __syncthreads();

    // phase 3: counting-sort local edge offsets (dstA re-read, streaming/L2-hot)
    for (int j = t; j < nLoc; j += ATHREADS) {
        int i2 = begin + j;
        int d = (i2 < E) ? dstA[i2] : (i2 - E);
        int slot = atomicAdd(&cur[d >> BSHIFT], 1);
        stage[slot] = (unsigned short)j;
    }
    __syncthreads();

    // phase 4: linear write-out; dstA/srcA re-read scattered (L1/L2-hot window)
    for (int j = t; j < nLoc; j += ATHREADS) {
        int loc = (int)stage[j];
        int i2 = begin + loc;
        int d = (i2 < E) ? dstA[i2] : (i2 - E);
        int s2 = (i2 < E) ? srcA[i2] : d;   // self-loop: s == d
        int b = d >> BSHIFT;
        int local = j - (cur[b] - cnt[b]);  // cur[b] = start+cnt after phase 3
        int slot = (int)gbase[b] + local;
        if (slot < BCAP)
            bucketBuf[(size_t)b * BCAP + slot] = ((unsigned)s2 << BSHIFT) | (d & (BNODES - 1));
    }
}

// Exclusive scan of bcnt[NBUCK] -> bstart; total -> rowStart[N]. Single block.
__global__ __launch_bounds__(512) void k_scanbuck(const int* __restrict__ bcnt,
                                                  int* __restrict__ bstart,
                                                  int* __restrict__ rowStartN,
                                                  int NBUCK) {
    __shared__ int wsum[8];
    int t = threadIdx.x;
    int v[4];
    int psum = 0;
#pragma unroll
    for (int q = 0; q < 4; ++q) {
        int b = t * 4 + q;
        v[q] = (b < NBUCK) ? bcnt[b] : 0;
        psum += v[q];
    }
    int lane = t & 63, w = t >> 6;
    int s = psum;
#pragma unroll
    for (int off = 1; off < 64; off <<= 1) {
        int u = __shfl_up(s, off, 64);
        if (lane >= off) s += u;
    }
    if (lane == 63) wsum[w] = s;
    __syncthreads();
    if (t < 8) {
        int x = wsum[t];
#pragma unroll
        for (int off = 1; off < 8; off <<= 1) {
            int u = __shfl_up(x, off, 64);
            if (t >= off) x += u;
        }
        wsum[t] = x;
    }
    __syncthreads();
    int run = ((w > 0) ? wsum[w - 1] : 0) + s - psum;
#pragma unroll
    for (int q = 0; q < 4; ++q) {
        int b = t * 4 + q;
        if (b < NBUCK) bstart[b] = run;
        run += v[q];
    }
    if (t == 511) *rowStartN = run;  // total = E + N
}

// Pass B: per-bucket counting sort by node. Wave-private histograms + wave-
// private scatter cursors (8x less LDS atomic contention; order within a
// node's run is free to permute -- sums are order-free). Wave 0 does the
// 64-wide scan and assigns per-wave sub-run bases.
__global__ __launch_bounds__(FB_THREADS) void k_fillB(
        const int* __restrict__ bcnt, const unsigned* __restrict__ bucketBuf,
        const int* __restrict__ bstart, int* __restrict__ rowStart,
        float* __restrict__ dinv, int* __restrict__ srcList, int N) {
    __shared__ int cntw[FB_WAVES][BNODES];   // 2 KB
    __shared__ int curw[FB_WAVES][BNODES];   // 2 KB
    __shared__ unsigned stage[BCAP];         // 16 KB
    int b = blockIdx.x;
    int t = threadIdx.x;
    int w = t >> 6, lane = t & 63;
    cntw[w][lane] = 0;
    __syncthreads();
    int n = bcnt[b];
    if (n > BCAP) n = BCAP;
    int base = bstart[b];
    const unsigned* buf = bucketBuf + (size_t)b * BCAP;
    for (int e = t; e < n; e += FB_THREADS)
        atomicAdd(&cntw[w][buf[e] & (BNODES - 1)], 1);
    __syncthreads();
    if (w == 0) {
        // lane == node id within bucket
        int tot = 0;
        int pre[FB_WAVES];
#pragma unroll
        for (int ww = 0; ww < FB_WAVES; ++ww) { pre[ww] = tot; tot += cntw[ww][lane]; }
        int s = tot;
#pragma unroll
        for (int off = 1; off < BNODES; off <<= 1) {
            int u = __shfl_up(s, off, 64);
            if (lane >= off) s += u;
        }
        int excl = s - tot;
        int node = b * BNODES + lane;
        if (node < N) {
            rowStart[node] = base + excl;
            dinv[node] = rsqrtf((float)tot);   // tot >= 1 (self-loop)
        }
#pragma unroll
        for (int ww = 0; ww < FB_WAVES; ++ww) curw[ww][lane] = excl + pre[ww];
    }
    __syncthreads();
    for (int e = t; e < n; e += FB_THREADS) {
        unsigned entry = buf[e];
        int slot = atomicAdd(&curw[w][entry & (BNODES - 1)], 1);
        stage[slot] = entry;
    }
    __syncthreads();
    for (int j = t; j < n; j += FB_THREADS)
        srcList[base + j] = (int)(stage[j] >> BSHIFT);
}

// ---------- MFMA GEMM: Hs = bf16((X@W)*dinv), 64x64 tile, K-blocked by 64 ----------
// Error-compensated bf16 splits: F32IN: X=Xh+Xl, W=Wh+Wl, D = Xh*Wh + Xh*Wl + Xl*Wh
// (drops Xl*Wl <= 2^-16 rel). !F32IN: X exact bf16, D = X*Wh + X*Wl.
// A/B fragment packing uses k = 8*(lane>>4)+j for BOTH operands. C/D layout is
// HW-fixed: row = 4*(lane>>4)+reg, col = lane&15 (verified round 4).
template <int K, bool F32IN>
__global__ __launch_bounds__(256) void k_gemm_mfma(const void* __restrict__ Xv,
                                                   const float* __restrict__ W,
                                                   const float* __restrict__ dinv,
                                                   unsigned short* __restrict__ Hs,
                                                   int N) {
    __shared__ unsigned short AH[64][72];
    __shared__ unsigned short AL[64][72];
    __shared__ unsigned short BH[64][72];
    __shared__ unsigned short BL[64][72];
    int t = threadIdx.x;
    int row0 = blockIdx.x * 64;
    if (F32IN && blockIdx.x == 0 && t < 32)   // zero row N of Hs (agg mask target)
        ((unsigned*)Hs)[(size_t)N * 32 + t] = 0u;
    int w = t >> 6, lane = t & 63;
    int lr = lane & 15, lh = lane >> 4;
    f32x4 acc[4];
#pragma unroll
    for (int tn = 0; tn < 4; ++tn) acc[tn] = (f32x4){0.f, 0.f, 0.f, 0.f};

    for (int kb = 0; kb < K; kb += 64) {
        if (kb) __syncthreads();
        // ---- stage A tile (rows row0..+63, k-cols kb..kb+63) ----
        if constexpr (F32IN) {
            const float* X = (const float*)Xv;
#pragma unroll
            for (int qq = 0; qq < 4; ++qq) {
                int f = qq * 256 + t;
                int r = f >> 4, c4 = (f & 15) << 2;
                int row = row0 + r;
                float4 x = make_float4(0.f, 0.f, 0.f, 0.f);
                if (row < N) x = *(const float4*)&X[(size_t)row * K + kb + c4];
                unsigned u01 = cvtpk(x.x, x.y), u23 = cvtpk(x.z, x.w);
                float l0 = x.x - bflo(u01);
                float l1 = x.y - __uint_as_float(u01 & 0xffff0000u);
                float l2 = x.z - bflo(u23);
                float l3 = x.w - __uint_as_float(u23 & 0xffff0000u);
                unsigned v01 = cvtpk(l0, l1), v23 = cvtpk(l2, l3);
                *(uint2*)&AH[r][c4] = make_uint2(u01, u23);
                *(uint2*)&AL[r][c4] = make_uint2(v01, v23);
            }
        } else {
            const unsigned* X = (const unsigned*)Xv;   // bf16 pairs [N][32]
#pragma unroll
            for (int qq = 0; qq < 2; ++qq) {
                int f = qq * 256 + t;
                int r = f >> 3, c8 = (f & 7) << 3;
                int row = row0 + r;
                uint4 v = make_uint4(0u, 0u, 0u, 0u);
                if (row < N) v = *(const uint4*)&X[(size_t)row * 32 + (c8 >> 1)];
                *(uint4*)&AH[r][c8] = v;
            }
        }
        // ---- stage B = W^T slice (k rows kb..kb+63, all 64 n), hi/lo ----
        {
            int n = (t & 15) + ((t >> 6) << 4);
            int kc0 = ((t >> 4) & 3) << 2;
#pragma unroll
            for (int qq = 0; qq < 4; ++qq) {
                int kc = kc0 + (qq << 4);
                float w0 = W[(size_t)(kb + kc + 0) * HIDD + n];
                float w1 = W[(size_t)(kb + kc + 1) * HIDD + n];
                float w2 = W[(size_t)(kb + kc + 2) * HIDD + n];
                float w3 = W[(size_t)(kb + kc + 3) * HIDD + n];
                unsigned u01 = cvtpk(w0, w1), u23 = cvtpk(w2, w3);
                float l0 = w0 - bflo(u01);
                float l1 = w1 - __uint_as_float(u01 & 0xffff0000u);
                float l2 = w2 - bflo(u23);
                float l3 = w3 - __uint_as_float(u23 & 0xffff0000u);
                unsigned v01 = cvtpk(l0, l1), v23 = cvtpk(l2, l3);
                *(uint2*)&BH[n][kc] = make_uint2(u01, u23);
                *(uint2*)&BL[n][kc] = make_uint2(v01, v23);
            }
        }
        __syncthreads();
        // ---- fragments + MFMA ----
#pragma unroll
        for (int s = 0; s < 2; ++s) {
            short8 ah = *(const short8*)&AH[16 * w + lr][32 * s + 8 * lh];
#pragma unroll
            for (int tn = 0; tn < 4; ++tn) {
                short8 bh = *(const short8*)&BH[16 * tn + lr][32 * s + 8 * lh];
                short8 bl = *(const short8*)&BL[16 * tn + lr][32 * s + 8 * lh];
                acc[tn] = __builtin_amdgcn_mfma_f32_16x16x32_bf16(ah, bh, acc[tn], 0, 0, 0);
                acc[tn] = __builtin_amdgcn_mfma_f32_16x16x32_bf16(ah, bl, acc[tn], 0, 0, 0);
                if constexpr (F32IN) {
                    short8 al = *(const short8*)&AL[16 * w + lr][32 * s + 8 * lh];
                    acc[tn] = __builtin_amdgcn_mfma_f32_16x16x32_bf16(al, bh, acc[tn], 0, 0, 0);
                }
            }
        }
    }
    // ---- epilogue: D row = 4*lh + r, col = 16*tn + lr ----
    int rb = row0 + 16 * w + 4 * lh;
#pragma unroll
    for (int r = 0; r < 4; ++r) {
        int row = rb + r;
        if (row < N) {
            float di = dinv[row];
#pragma unroll
            for (int tn = 0; tn < 4; ++tn)
                Hs[(size_t)row * HIDD + 16 * tn + lr] = f2bf(acc[tn][r] * di);
        }
    }
}

// ---------- aggregation: wave per TWO nodes; 8 edge slots x 8 lanes (16B/lane).
// Round-5 structure (measured best): fixed straight-line 48-edge masked window
// per node, all 12 gathers issued back-to-back. Masked slots redirect to the
// L1-hot zero row N. Rare degree>48 drained by unmasked 32-edge pre-loops.
// Accumulate: per uint PAIR one v_pk_add_f32 eats raw hi-bf16 halves (garbage
// <= 2^-8 rel), one eats shifted lo halves: 8 VALU / uint4.

#define PK2(accH, accL, u0, u1)                                              \
    do {                                                                     \
        f32x2 hh_, ll_;                                                      \
        hh_.x = __uint_as_float(u0);                                         \
        hh_.y = __uint_as_float(u1);                                         \
        ll_.x = __uint_as_float((u0) << 16);                                 \
        ll_.y = __uint_as_float((u1) << 16);                                 \
        asm("v_pk_add_f32 %0, %1, %0" : "+v"(accH) : "v"(hh_));              \
        asm("v_pk_add_f32 %0, %1, %0" : "+v"(accL) : "v"(ll_));              \
    } while (0)

#define ACC4(H0, L0, H1, L1, v4)                                             \
    do { PK2(H0, L0, (v4).x, (v4).y); PK2(H1, L1, (v4).z, (v4).w); } while (0)

#define ROWG(sidx) (*(const uint4*)(Hb + (((unsigned)(sidx) << 7) + qb)))

#define SRC6(P, ebeg, eend)                                                  \
    int P##b = (ebeg) + g;                                                   \
    int P##s0 = (P##b      < (eend)) ? srcList[P##b]      : N;               \
    int P##s1 = (P##b + 8  < (eend)) ? srcList[P##b + 8]  : N;               \
    int P##s2 = (P##b + 16 < (eend)) ? srcList[P##b + 16] : N;               \
    int P##s3 = (P##b + 24 < (eend)) ? srcList[P##b + 24] : N;               \
    int P##s4 = (P##b + 32 < (eend)) ? srcList[P##b + 32] : N;               \
    int P##s5 = (P##b + 40 < (eend)) ? srcList[P##b + 40] : N

#define GATH6(P)                                                             \
    uint4 P##v0 = ROWG(P##s0); uint4 P##v1 = ROWG(P##s1);                    \
    uint4 P##v2 = ROWG(P##s2); uint4 P##v3 = ROWG(P##s3);                    \
    uint4 P##v4 = ROWG(P##s4); uint4 P##v5 = ROWG(P##s5)

#define ACC6(P, H0, L0, H1, L1)                                              \
    do { ACC4(H0, L0, H1, L1, P##v0); ACC4(H0, L0, H1, L1, P##v1);           \
         ACC4(H0, L0, H1, L1, P##v2); ACC4(H0, L0, H1, L1, P##v3);           \
         ACC4(H0, L0, H1, L1, P##v4); ACC4(H0, L0, H1, L1, P##v5); } while (0)

#define BIGLOOP(ePos, eEnd, H0, L0, H1, L1)                                  \
    while ((eEnd) - (ePos) > 48) {  /* rare: degree > 48 */                  \
        int s0 = srcList[(ePos) + g];                                        \
        int s1 = srcList[(ePos) + 8 + g];                                    \
        int s2 = srcList[(ePos) + 16 + g];                                   \
        int s3 = srcList[(ePos) + 24 + g];                                   \
        uint4 v0 = ROWG(s0); uint4 v1 = ROWG(s1);                            \
        uint4 v2 = ROWG(s2); uint4 v3 = ROWG(s3);                            \
        ACC4(H0, L0, H1, L1, v0); ACC4(H0, L0, H1, L1, v1);                  \
        ACC4(H0, L0, H1, L1, v2); ACC4(H0, L0, H1, L1, v3);                  \
        (ePos) += 32;                                                        \
    }

// shared pair body: accumulates nodes i0,i1 into v8A/v8B (reduced across wave)
#define AGG_PAIR(HPTR)                                                       \
    const char* Hb = (const char*)(HPTR);                                    \
    unsigned qb = (unsigned)q << 4;                                          \
    int2 ra = *(const int2*)&rowStart[i0];                                   \
    int rc = rowStart[i0 + 2];                                               \
    int beg0 = ra.x, end0 = ra.y;                                            \
    int beg1 = (i1 == i0) ? ra.x : ra.y;                                     \
    int end1 = (i1 == i0) ? ra.y : rc;                                       \
    f32x2 h0A = {0.f,0.f}, l0A = {0.f,0.f}, h1A = {0.f,0.f}, l1A = {0.f,0.f};\
    f32x2 h0B = {0.f,0.f}, l0B = {0.f,0.f}, h1B = {0.f,0.f}, l1B = {0.f,0.f};\
    int e0 = beg0, e1 = beg1;                                                \
    BIGLOOP(e0, end0, h0A, l0A, h1A, l1A)                                    \
    BIGLOOP(e1, end1, h0B, l0B, h1B, l1B)                                    \
    SRC6(A, e0, end0);                                                       \
    SRC6(B, e1, end1);                                                       \
    GATH6(A);                                                                \
    GATH6(B);                                                                \
    ACC6(A, h0A, l0A, h1A, l1A);                                             \
    ACC6(B, h0B, l0B, h1B, l1B);                                             \
    float v8A[8] = {l0A.x, h0A.x, l0A.y, h0A.y, l1A.x, h1A.x, l1A.y, h1A.y}; \
    float v8B[8] = {l0B.x, h0B.x, l0B.y, h0B.y, l1B.x, h1B.x, l1B.y, h1B.y}; \
    _Pragma("unroll")                                                        \
    for (int k = 0; k < 8; ++k) {                                            \
        v8A[k] += __shfl_xor(v8A[k], 8, 64);                                 \
        v8A[k] += __shfl_xor(v8A[k], 16, 64);                                 \
        v8A[k] += __shfl_xor(v8A[k], 32, 64);                                 \
        v8B[k] += __shfl_xor(v8B[k], 8, 64);                                 \
        v8B[k] += __shfl_xor(v8B[k], 16, 64);                                 \
        v8B[k] += __shfl_xor(v8B[k], 32, 64);                                 \
    }

__global__ __launch_bounds__(256) void k_agg_relu(
        const unsigned* __restrict__ Hs, const float* __restrict__ dinv,
        const int* __restrict__ rowStart, const int* __restrict__ srcList,
        const float* __restrict__ bias, unsigned* __restrict__ O, int N) {
    int wid  = (blockIdx.x * blockDim.x + threadIdx.x) >> 6;
    int lane = threadIdx.x & 63;
    int i0 = 2 * wid;
    if (i0 >= N) return;
    i0 = __builtin_amdgcn_readfirstlane(i0);
    int i1 = (i0 + 1 < N) ? i0 + 1 : i0;
    int g = lane >> 3;   // edge slot 0..7
    int q = lane & 7;    // 16B slice of the row
    AGG_PAIR(Hs)
    if (g < 2) {
        int io = g ? i1 : i0;
        float u0 = g ? v8B[0] : v8A[0];
        float u1 = g ? v8B[1] : v8A[1];
        float u2 = g ? v8B[2] : v8A[2];
        float u3 = g ? v8B[3] : v8A[3];
        float u4 = g ? v8B[4] : v8A[4];
        float u5 = g ? v8B[5] : v8A[5];
        float u6 = g ? v8B[6] : v8A[6];
        float u7 = g ? v8B[7] : v8A[7];
        float di = dinv[io];
        float4 ba = *(const float4*)&bias[q * 8];
        float4 bb = *(const float4*)&bias[q * 8 + 4];
        const float* bp = (const float*)&ba;
        const float* bq = (const float*)&bb;
        float r0 = fmaxf(di * u0 + bp[0], 0.f);
        float r1 = fmaxf(di * u1 + bp[1], 0.f);
        float r2 = fmaxf(di * u2 + bp[2], 0.f);
        float r3 = fmaxf(di * u3 + bp[3], 0.f);
        float r4 = fmaxf(di * u4 + bq[0], 0.f);
        float r5 = fmaxf(di * u5 + bq[1], 0.f);
        float r6 = fmaxf(di * u6 + bq[2], 0.f);
        float r7 = fmaxf(di * u7 + bq[3], 0.f);
        uint4 o;
        o.x = cvtpk(r0, r1);
        o.y = cvtpk(r2, r3);
        o.z = cvtpk(r4, r5);
        o.w = cvtpk(r6, r7);
        *(uint4*)(O + (size_t)io * 32 + q * 4) = o;
    }
}

__global__ __launch_bounds__(256) void k_agg_fc(
        const unsigned* __restrict__ Hs, const float* __restrict__ dinv,
        const int* __restrict__ rowStart, const int* __restrict__ srcList,
        const float* __restrict__ b2, const float* __restrict__ Wfc,
        const float* __restrict__ bfc, float* __restrict__ out, int N) {
    int wid  = (blockIdx.x * blockDim.x + threadIdx.x) >> 6;
    int lane = threadIdx.x & 63;
    int i0 = 2 * wid;
    if (i0 >= N) return;
    i0 = __builtin_amdgcn_readfirstlane(i0);
    int i1 = (i0 + 1 < N) ? i0 + 1 : i0;
    int g = lane >> 3;
    int q = lane & 7;
    AGG_PAIR(Hs)
    if (g < 2) {
        int io = g ? i1 : i0;
        float u0 = g ? v8B[0] : v8A[0];
        float u1 = g ? v8B[1] : v8A[1];
        float u2 = g ? v8B[2] : v8A[2];
        float u3 = g ? v8B[3] : v8A[3];
        float u4 = g ? v8B[4] : v8A[4];
        float u5 = g ? v8B[5] : v8A[5];
        float u6 = g ? v8B[6] : v8A[6];
        float u7 = g ? v8B[7] : v8A[7];
        float di = dinv[io];
        float4 ba = *(const float4*)&b2[q * 8];
        float4 bb = *(const float4*)&b2[q * 8 + 4];
        float4 wa = *(const float4*)&Wfc[q * 8];
        float4 wb = *(const float4*)&Wfc[q * 8 + 4];
        const float* bp = (const float*)&ba;
        const float* bq = (const float*)&bb;
        const float* wp = (const float*)&wa;
        const float* wq = (const float*)&wb;
        float p = fmaxf(di * u0 + bp[0], 0.f) * wp[0]
                + fmaxf(di * u1 + bp[1], 0.f) * wp[1]
                + fmaxf(di * u2 + bp[2], 0.f) * wp[2]
                + fmaxf(di * u3 + bp[3], 0.f) * wp[3]
                + fmaxf(di * u4 + bq[0], 0.f) * wq[0]
                + fmaxf(di * u5 + bq[1], 0.f) * wq[1]
                + fmaxf(di * u6 + bq[2], 0.f) * wq[2]
                + fmaxf(di * u7 + bq[3], 0.f) * wq[3];
        p += __shfl_xor(p, 1, 64);
        p += __shfl_xor(p, 2, 64);
        p += __shfl_xor(p, 4, 64);
        if (q == 0) {
            float z = p + bfc[0];
            out[io] = 1.f / (1.f + __expf(-z));
        }
    }
}

// ---------------- host ----------------

extern "C" void kernel_launch(void* const* d_in, const int* in_sizes, int n_in,
                              void* d_out, int out_size, void* d_ws, size_t ws_size,
                              hipStream_t stream) {
    const float* x   = (const float*)d_in[0];
    const int*   ei  = (const int*)d_in[1];
    const float* W1  = (const float*)d_in[2];
    const float* b1  = (const float*)d_in[3];
    const float* W2  = (const float*)d_in[4];
    const float* b2  = (const float*)d_in[5];
    const float* Wfc = (const float*)d_in[6];
    const float* bfc = (const float*)d_in[7];
    float* out = (float*)d_out;

    int N  = in_sizes[0] / INDIM;   // 100000
    int E  = in_sizes[1] / 2;       // 3200000
    int EV = E + N;
    const int* srcA = ei;
    const int* dstA = ei + E;

    int NBUCK = (N + BNODES - 1) / BNODES;          // 1563 (<= MAXBUCK)
    size_t bucketBytes = (size_t)NBUCK * BCAP * 4;  // ~25.6 MB
    size_t hsBytes     = (size_t)(N + 1) * HIDD * 2; // bf16, +1 zero row

    char* ws = (char*)d_ws;
    size_t off = 0;
    auto alloc = [&](size_t bytes) -> char* {
        char* p = ws + off;
        off = (off + bytes + 255) & ~(size_t)255;
        return p;
    };
    int*   rowStart = (int*)alloc((size_t)(N + 9) * 4);   // +pad for pair reads
    float* dinv     = (float*)alloc((size_t)N * 4);
    int*   bcnt     = (int*)alloc((size_t)NBUCK * 4);
    int*   bstart   = (int*)alloc((size_t)NBUCK * 4);
    int*   srcList  = (int*)alloc((size_t)(EV + 48) * 4); // +48 pad for window loads
    char*  region   = alloc(bucketBytes > hsBytes ? bucketBytes : hsBytes);
    unsigned*       bucketBuf = (unsigned*)region;        // aliased with Hs
    unsigned short* Hs        = (unsigned short*)region;  // bf16 [N+1][64]
    unsigned* bufB = (unsigned*)alloc(hsBytes);           // bf16 [N+1][64] relu(agg1)

    hipMemsetAsync(bcnt, 0, (size_t)NBUCK * 4, stream);
    int aBlocks = (EV + CHUNK - 1) / CHUNK;  // 202
    hipLaunchKernelGGL(k_bucketA, dim3(aBlocks), dim3(ATHREADS), 0, stream,
                       srcA, dstA, bcnt, bucketBuf, E, N, NBUCK);
    hipLaunchKernelGGL(k_scanbuck, dim3(1), dim3(512), 0, stream,
                       bcnt, bstart, rowStart + N, NBUCK);
    hipLaunchKernelGGL(k_fillB, dim3(NBUCK), dim3(FB_THREADS), 0, stream,
                       bcnt, bucketBuf, bstart, rowStart, dinv, srcList, N);

    int gBlocks = (N + 63) / 64;  // 1563
    hipLaunchKernelGGL((k_gemm_mfma<INDIM, true>), dim3(gBlocks), dim3(256), 0, stream,
                       (const void*)x, W1, dinv, Hs, N);

    int aggWaves  = (N + 1) / 2;               // two nodes per wave
    int aggBlocks = (aggWaves + 3) / 4;        // 4 waves per block
    hipLaunchKernelGGL(k_agg_relu, dim3(aggBlocks), dim3(256), 0, stream,
                       (const unsigned*)Hs, dinv, rowStart, srcList, b1, bufB, N);

    hipLaunchKernelGGL((k_gemm_mfma<HIDD, false>), dim3(gBlocks), dim3(256), 0, stream,
                       (const void*)bufB, W2, dinv, Hs, N);

    hipLaunchKernelGGL(k_agg_fc, dim3(aggBlocks), dim3(256), 0, stream,
                       (const unsigned*)Hs, dinv, rowStart, srcList, b2, Wfc, bfc, out, N);
}

// Round 10
// 176.015 us; speedup vs baseline: 1.1794x; 1.1794x over previous
//
#include <hip/hip_runtime.h>

#define INDIM 128
#define HIDD 64
#define BSHIFT 6                 // 64 nodes per bucket
#define BNODES 64
#define BCAP 4096                // per-bucket capacity (mean fill ~2112)
#define MAXBUCK 2048             // bucket-array capacity (N<=131072)
#define CHUNK 8192               // edges per block in pass A (403 blocks)
#define ATHREADS 1024            // 16 waves/block: latency hiding w/o touching locality
#define BPT (MAXBUCK / ATHREADS) // 2
#define FB_THREADS 512
#define FB_WAVES (FB_THREADS / 64)

typedef float f32x2 __attribute__((ext_vector_type(2)));
using short8 = __attribute__((ext_vector_type(8))) short;   // 8 bf16 (4 VGPRs)
using f32x4  = __attribute__((ext_vector_type(4))) float;   // MFMA acc

__device__ inline unsigned short f2bf(float f) {   // RNE f32->bf16
    unsigned u = __float_as_uint(f);
    return (unsigned short)((u + 0x7fff + ((u >> 16) & 1)) >> 16);
}
__device__ inline float bflo(unsigned v) { return __uint_as_float(v << 16); }
__device__ inline unsigned cvtpk(float a, float b) {  // {bf16(a), bf16(b)<<16} RNE
    unsigned r;
    asm("v_cvt_pk_bf16_f32 %0, %1, %2" : "=v"(r) : "v"(a), "v"(b));
    return r;
}

// ---------------- CSR build ----------------

// Pass A: per-block LDS counting sort of CHUNK edges by destination bucket.
// Round-8 memory structure kept EXACTLY (dLds cache of dstA -- round-9 lesson:
// dropping it lets concurrent blocks' bucketBuf writes evict the window from
// L2, FETCH 26->88 MB; and CHUNK must stay 8192 so grid=403 > 256 CUs).
// Round-10 change: 1024 threads (16 waves/block) -- doubles waves/CU for the
// latency-bound LDS-atomic phase chain without touching the memory layout.
// NO nontemporal hints (round-7 lesson: nt on the scattered phase-4 read =
// 2.7x HBM over-fetch).
__global__ __launch_bounds__(ATHREADS, 8) void k_bucketA(
        const int* __restrict__ srcA, const int* __restrict__ dstA,
        int* __restrict__ bcnt, unsigned* __restrict__ bucketBuf,
        int E, int N, int NBUCK) {
    __shared__ int cnt[MAXBUCK];              // 8 KB
    __shared__ int cur[MAXBUCK];              // 8 KB
    __shared__ unsigned short gbase[MAXBUCK]; // 4 KB
    __shared__ unsigned short stage[CHUNK];   // 16 KB (local edge offsets)
    __shared__ int dLds[CHUNK];               // 32 KB (cached destinations)
    __shared__ int wsum[ATHREADS / 64];
    int t = threadIdx.x;
    int EV = E + N;
    int begin = blockIdx.x * CHUNK;
    int end = begin + CHUNK;
    if (end > EV) end = EV;
    if (begin >= EV) return;
    int nLoc = end - begin;

    for (int b = t; b < MAXBUCK; b += ATHREADS) cnt[b] = 0;
    __syncthreads();

    // phase 1: single global read of dstA; histogram + cache d in LDS
    for (int i = begin + t; i < end; i += ATHREADS) {
        int d = (i < E) ? dstA[i] : (i - E);
        dLds[i - begin] = d;
        atomicAdd(&cnt[d >> BSHIFT], 1);
    }
    __syncthreads();

    // phase 2a: exclusive scan of cnt via wave shuffles
    int vq[BPT];
    int psum = 0;
#pragma unroll
    for (int q = 0; q < BPT; ++q) { vq[q] = cnt[t * BPT + q]; psum += vq[q]; }
    int lane = t & 63, w = t >> 6;
    int s = psum;
#pragma unroll
    for (int off = 1; off < 64; off <<= 1) {
        int u = __shfl_up(s, off, 64);
        if (lane >= off) s += u;
    }
    if (lane == 63) wsum[w] = s;
    __syncthreads();
    if (t < ATHREADS / 64) {
        int x = wsum[t];
#pragma unroll
        for (int off = 1; off < ATHREADS / 64; off <<= 1) {
            int u = __shfl_up(x, off, 64);
            if (t >= off) x += u;
        }
        wsum[t] = x;   // inclusive wave sums
    }
    __syncthreads();
    int run = ((w > 0) ? wsum[w - 1] : 0) + s - psum;
#pragma unroll
    for (int q = 0; q < BPT; ++q) {
        cur[t * BPT + q] = run;
        run += vq[q];
    }

    // phase 2b: reserve global runs (staggered sweep start per block)
    int b0 = (int)(((unsigned)blockIdx.x * 683u) % (unsigned)NBUCK);
    for (int idx = t; idx < NBUCK; idx += ATHREADS) {
        int b = idx + b0;
        if (b >= NBUCK) b -= NBUCK;
        int c = cnt[b];
        gbase[b] = (unsigned short)((c > 0) ? atomicAdd(&bcnt[b], c) : 0);
    }
    __syncthreads();

    // phase 3: counting-sort local edge offsets (LDS-only)
    for (int j = t; j < nLoc; j += ATHREADS) {
        int d = dLds[j];
        int slot = atomicAdd(&cur[d >> BSHIFT], 1);
        stage[slot] = (unsigned short)j;
    }
    __syncthreads();

    // phase 4: linear write-out; d from LDS, only srcA read from global
    for (int j = t; j < nLoc; j += ATHREADS) {
        int loc = (int)stage[j];
        int d = dLds[loc];
        int i2 = begin + loc;
        int s2 = (i2 < E) ? srcA[i2] : d;   // self-loop: s == d
        int b = d >> BSHIFT;
        int local = j - (cur[b] - cnt[b]);  // cur[b] = start+cnt after phase 3
        int slot = (int)gbase[b] + local;
        if (slot < BCAP)
            bucketBuf[(size_t)b * BCAP + slot] = ((unsigned)s2 << BSHIFT) | (d & (BNODES - 1));
    }
}

// Exclusive scan of bcnt[NBUCK] -> bstart; total -> rowStart[N]. Single block.
__global__ __launch_bounds__(512) void k_scanbuck(const int* __restrict__ bcnt,
                                                  int* __restrict__ bstart,
                                                  int* __restrict__ rowStartN,
                                                  int NBUCK) {
    __shared__ int wsum[8];
    int t = threadIdx.x;
    int v[4];
    int psum = 0;
#pragma unroll
    for (int q = 0; q < 4; ++q) {
        int b = t * 4 + q;
        v[q] = (b < NBUCK) ? bcnt[b] : 0;
        psum += v[q];
    }
    int lane = t & 63, w = t >> 6;
    int s = psum;
#pragma unroll
    for (int off = 1; off < 64; off <<= 1) {
        int u = __shfl_up(s, off, 64);
        if (lane >= off) s += u;
    }
    if (lane == 63) wsum[w] = s;
    __syncthreads();
    if (t < 8) {
        int x = wsum[t];
#pragma unroll
        for (int off = 1; off < 8; off <<= 1) {
            int u = __shfl_up(x, off, 64);
            if (t >= off) x += u;
        }
        wsum[t] = x;
    }
    __syncthreads();
    int run = ((w > 0) ? wsum[w - 1] : 0) + s - psum;
#pragma unroll
    for (int q = 0; q < 4; ++q) {
        int b = t * 4 + q;
        if (b < NBUCK) bstart[b] = run;
        run += v[q];
    }
    if (t == 511) *rowStartN = run;  // total = E + N
}

// Pass B: per-bucket counting sort by node. Wave-private histograms + wave-
// private scatter cursors (8x less LDS atomic contention; order within a
// node's run is free to permute -- sums are order-free). Wave 0 does the
// 64-wide scan and assigns per-wave sub-run bases.
__global__ __launch_bounds__(FB_THREADS) void k_fillB(
        const int* __restrict__ bcnt, const unsigned* __restrict__ bucketBuf,
        const int* __restrict__ bstart, int* __restrict__ rowStart,
        float* __restrict__ dinv, int* __restrict__ srcList, int N) {
    __shared__ int cntw[FB_WAVES][BNODES];   // 2 KB
    __shared__ int curw[FB_WAVES][BNODES];   // 2 KB
    __shared__ unsigned stage[BCAP];         // 16 KB
    int b = blockIdx.x;
    int t = threadIdx.x;
    int w = t >> 6, lane = t & 63;
    cntw[w][lane] = 0;
    __syncthreads();
    int n = bcnt[b];
    if (n > BCAP) n = BCAP;
    int base = bstart[b];
    const unsigned* buf = bucketBuf + (size_t)b * BCAP;
    for (int e = t; e < n; e += FB_THREADS)
        atomicAdd(&cntw[w][buf[e] & (BNODES - 1)], 1);
    __syncthreads();
    if (w == 0) {
        // lane == node id within bucket
        int tot = 0;
        int pre[FB_WAVES];
#pragma unroll
        for (int ww = 0; ww < FB_WAVES; ++ww) { pre[ww] = tot; tot += cntw[ww][lane]; }
        int s = tot;
#pragma unroll
        for (int off = 1; off < BNODES; off <<= 1) {
            int u = __shfl_up(s, off, 64);
            if (lane >= off) s += u;
        }
        int excl = s - tot;
        int node = b * BNODES + lane;
        if (node < N) {
            rowStart[node] = base + excl;
            dinv[node] = rsqrtf((float)tot);   // tot >= 1 (self-loop)
        }
#pragma unroll
        for (int ww = 0; ww < FB_WAVES; ++ww) curw[ww][lane] = excl + pre[ww];
    }
    __syncthreads();
    for (int e = t; e < n; e += FB_THREADS) {
        unsigned entry = buf[e];
        int slot = atomicAdd(&curw[w][entry & (BNODES - 1)], 1);
        stage[slot] = entry;
    }
    __syncthreads();
    for (int j = t; j < n; j += FB_THREADS)
        srcList[base + j] = (int)(stage[j] >> BSHIFT);
}

// ---------- MFMA GEMM: Hs = bf16((X@W)*dinv), 64x64 tile, K-blocked by 64 ----------
// Error-compensated bf16 splits: F32IN: X=Xh+Xl, W=Wh+Wl, D = Xh*Wh + Xh*Wl + Xl*Wh
// (drops Xl*Wl <= 2^-16 rel). !F32IN: X exact bf16, D = X*Wh + X*Wl.
// A/B fragment packing uses k = 8*(lane>>4)+j for BOTH operands. C/D layout is
// HW-fixed: row = 4*(lane>>4)+reg, col = lane&15 (verified round 4).
template <int K, bool F32IN>
__global__ __launch_bounds__(256) void k_gemm_mfma(const void* __restrict__ Xv,
                                                   const float* __restrict__ W,
                                                   const float* __restrict__ dinv,
                                                   unsigned short* __restrict__ Hs,
                                                   int N) {
    __shared__ unsigned short AH[64][72];
    __shared__ unsigned short AL[64][72];
    __shared__ unsigned short BH[64][72];
    __shared__ unsigned short BL[64][72];
    int t = threadIdx.x;
    int row0 = blockIdx.x * 64;
    if (F32IN && blockIdx.x == 0 && t < 32)   // zero row N of Hs (agg mask target)
        ((unsigned*)Hs)[(size_t)N * 32 + t] = 0u;
    int w = t >> 6, lane = t & 63;
    int lr = lane & 15, lh = lane >> 4;
    f32x4 acc[4];
#pragma unroll
    for (int tn = 0; tn < 4; ++tn) acc[tn] = (f32x4){0.f, 0.f, 0.f, 0.f};

    for (int kb = 0; kb < K; kb += 64) {
        if (kb) __syncthreads();
        // ---- stage A tile (rows row0..+63, k-cols kb..kb+63) ----
        if constexpr (F32IN) {
            const float* X = (const float*)Xv;
#pragma unroll
            for (int qq = 0; qq < 4; ++qq) {
                int f = qq * 256 + t;
                int r = f >> 4, c4 = (f & 15) << 2;
                int row = row0 + r;
                float4 x = make_float4(0.f, 0.f, 0.f, 0.f);
                if (row < N) x = *(const float4*)&X[(size_t)row * K + kb + c4];
                unsigned u01 = cvtpk(x.x, x.y), u23 = cvtpk(x.z, x.w);
                float l0 = x.x - bflo(u01);
                float l1 = x.y - __uint_as_float(u01 & 0xffff0000u);
                float l2 = x.z - bflo(u23);
                float l3 = x.w - __uint_as_float(u23 & 0xffff0000u);
                unsigned v01 = cvtpk(l0, l1), v23 = cvtpk(l2, l3);
                *(uint2*)&AH[r][c4] = make_uint2(u01, u23);
                *(uint2*)&AL[r][c4] = make_uint2(v01, v23);
            }
        } else {
            const unsigned* X = (const unsigned*)Xv;   // bf16 pairs [N][32]
#pragma unroll
            for (int qq = 0; qq < 2; ++qq) {
                int f = qq * 256 + t;
                int r = f >> 3, c8 = (f & 7) << 3;
                int row = row0 + r;
                uint4 v = make_uint4(0u, 0u, 0u, 0u);
                if (row < N) v = *(const uint4*)&X[(size_t)row * 32 + (c8 >> 1)];
                *(uint4*)&AH[r][c8] = v;
            }
        }
        // ---- stage B = W^T slice (k rows kb..kb+63, all 64 n), hi/lo ----
        {
            int n = (t & 15) + ((t >> 6) << 4);
            int kc0 = ((t >> 4) & 3) << 2;
#pragma unroll
            for (int qq = 0; qq < 4; ++qq) {
                int kc = kc0 + (qq << 4);
                float w0 = W[(size_t)(kb + kc + 0) * HIDD + n];
                float w1 = W[(size_t)(kb + kc + 1) * HIDD + n];
                float w2 = W[(size_t)(kb + kc + 2) * HIDD + n];
                float w3 = W[(size_t)(kb + kc + 3) * HIDD + n];
                unsigned u01 = cvtpk(w0, w1), u23 = cvtpk(w2, w3);
                float l0 = w0 - bflo(u01);
                float l1 = w1 - __uint_as_float(u01 & 0xffff0000u);
                float l2 = w2 - bflo(u23);
                float l3 = w3 - __uint_as_float(u23 & 0xffff0000u);
                unsigned v01 = cvtpk(l0, l1), v23 = cvtpk(l2, l3);
                *(uint2*)&BH[n][kc] = make_uint2(u01, u23);
                *(uint2*)&BL[n][kc] = make_uint2(v01, v23);
            }
        }
        __syncthreads();
        // ---- fragments + MFMA ----
#pragma unroll
        for (int s = 0; s < 2; ++s) {
            short8 ah = *(const short8*)&AH[16 * w + lr][32 * s + 8 * lh];
#pragma unroll
            for (int tn = 0; tn < 4; ++tn) {
                short8 bh = *(const short8*)&BH[16 * tn + lr][32 * s + 8 * lh];
                short8 bl = *(const short8*)&BL[16 * tn + lr][32 * s + 8 * lh];
                acc[tn] = __builtin_amdgcn_mfma_f32_16x16x32_bf16(ah, bh, acc[tn], 0, 0, 0);
                acc[tn] = __builtin_amdgcn_mfma_f32_16x16x32_bf16(ah, bl, acc[tn], 0, 0, 0);
                if constexpr (F32IN) {
                    short8 al = *(const short8*)&AL[16 * w + lr][32 * s + 8 * lh];
                    acc[tn] = __builtin_amdgcn_mfma_f32_16x16x32_bf16(al, bh, acc[tn], 0, 0, 0);
                }
            }
        }
    }
    // ---- epilogue: D row = 4*lh + r, col = 16*tn + lr ----
    int rb = row0 + 16 * w + 4 * lh;
#pragma unroll
    for (int r = 0; r < 4; ++r) {
        int row = rb + r;
        if (row < N) {
            float di = dinv[row];
#pragma unroll
            for (int tn = 0; tn < 4; ++tn)
                Hs[(size_t)row * HIDD + 16 * tn + lr] = f2bf(acc[tn][r] * di);
        }
    }
}

// ---------- aggregation: wave per TWO nodes; 8 edge slots x 8 lanes (16B/lane).
// Round-5 structure (measured best): fixed straight-line 48-edge masked window
// per node, all 12 gathers issued back-to-back. Masked slots redirect to the
// L1-hot zero row N. Rare degree>48 drained by unmasked 32-edge pre-loops.
// Accumulate: per uint PAIR one v_pk_add_f32 eats raw hi-bf16 halves (garbage
// <= 2^-8 rel), one eats shifted lo halves: 8 VALU / uint4.

#define PK2(accH, accL, u0, u1)                                              \
    do {                                                                     \
        f32x2 hh_, ll_;                                                      \
        hh_.x = __uint_as_float(u0);                                         \
        hh_.y = __uint_as_float(u1);                                         \
        ll_.x = __uint_as_float((u0) << 16);                                 \
        ll_.y = __uint_as_float((u1) << 16);                                 \
        asm("v_pk_add_f32 %0, %1, %0" : "+v"(accH) : "v"(hh_));              \
        asm("v_pk_add_f32 %0, %1, %0" : "+v"(accL) : "v"(ll_));              \
    } while (0)

#define ACC4(H0, L0, H1, L1, v4)                                             \
    do { PK2(H0, L0, (v4).x, (v4).y); PK2(H1, L1, (v4).z, (v4).w); } while (0)

#define ROWG(sidx) (*(const uint4*)(Hb + (((unsigned)(sidx) << 7) + qb)))

#define SRC6(P, ebeg, eend)                                                  \
    int P##b = (ebeg) + g;                                                   \
    int P##s0 = (P##b      < (eend)) ? srcList[P##b]      : N;               \
    int P##s1 = (P##b + 8  < (eend)) ? srcList[P##b + 8]  : N;               \
    int P##s2 = (P##b + 16 < (eend)) ? srcList[P##b + 16] : N;               \
    int P##s3 = (P##b + 24 < (eend)) ? srcList[P##b + 24] : N;               \
    int P##s4 = (P##b + 32 < (eend)) ? srcList[P##b + 32] : N;               \
    int P##s5 = (P##b + 40 < (eend)) ? srcList[P##b + 40] : N

#define GATH6(P)                                                             \
    uint4 P##v0 = ROWG(P##s0); uint4 P##v1 = ROWG(P##s1);                    \
    uint4 P##v2 = ROWG(P##s2); uint4 P##v3 = ROWG(P##s3);                    \
    uint4 P##v4 = ROWG(P##s4); uint4 P##v5 = ROWG(P##s5)

#define ACC6(P, H0, L0, H1, L1)                                              \
    do { ACC4(H0, L0, H1, L1, P##v0); ACC4(H0, L0, H1, L1, P##v1);           \
         ACC4(H0, L0, H1, L1, P##v2); ACC4(H0, L0, H1, L1, P##v3);           \
         ACC4(H0, L0, H1, L1, P##v4); ACC4(H0, L0, H1, L1, P##v5); } while (0)

#define BIGLOOP(ePos, eEnd, H0, L0, H1, L1)                                  \
    while ((eEnd) - (ePos) > 48) {  /* rare: degree > 48 */                  \
        int s0 = srcList[(ePos) + g];                                        \
        int s1 = srcList[(ePos) + 8 + g];                                    \
        int s2 = srcList[(ePos) + 16 + g];                                   \
        int s3 = srcList[(ePos) + 24 + g];                                   \
        uint4 v0 = ROWG(s0); uint4 v1 = ROWG(s1);                            \
        uint4 v2 = ROWG(s2); uint4 v3 = ROWG(s3);                            \
        ACC4(H0, L0, H1, L1, v0); ACC4(H0, L0, H1, L1, v1);                  \
        ACC4(H0, L0, H1, L1, v2); ACC4(H0, L0, H1, L1, v3);                  \
        (ePos) += 32;                                                        \
    }

// shared pair body: accumulates nodes i0,i1 into v8A/v8B (reduced across wave)
#define AGG_PAIR(HPTR)                                                       \
    const char* Hb = (const char*)(HPTR);                                    \
    unsigned qb = (unsigned)q << 4;                                          \
    int2 ra = *(const int2*)&rowStart[i0];                                   \
    int rc = rowStart[i0 + 2];                                               \
    int beg0 = ra.x, end0 = ra.y;                                            \
    int beg1 = (i1 == i0) ? ra.x : ra.y;                                     \
    int end1 = (i1 == i0) ? ra.y : rc;                                       \
    f32x2 h0A = {0.f,0.f}, l0A = {0.f,0.f}, h1A = {0.f,0.f}, l1A = {0.f,0.f};\
    f32x2 h0B = {0.f,0.f}, l0B = {0.f,0.f}, h1B = {0.f,0.f}, l1B = {0.f,0.f};\
    int e0 = beg0, e1 = beg1;                                                \
    BIGLOOP(e0, end0, h0A, l0A, h1A, l1A)                                    \
    BIGLOOP(e1, end1, h0B, l0B, h1B, l1B)                                    \
    SRC6(A, e0, end0);                                                       \
    SRC6(B, e1, end1);                                                       \
    GATH6(A);                                                                \
    GATH6(B);                                                                \
    ACC6(A, h0A, l0A, h1A, l1A);                                             \
    ACC6(B, h0B, l0B, h1B, l1B);                                             \
    float v8A[8] = {l0A.x, h0A.x, l0A.y, h0A.y, l1A.x, h1A.x, l1A.y, h1A.y}; \
    float v8B[8] = {l0B.x, h0B.x, l0B.y, h0B.y, l1B.x, h1B.x, l1B.y, h1B.y}; \
    _Pragma("unroll")                                                        \
    for (int k = 0; k < 8; ++k) {                                            \
        v8A[k] += __shfl_xor(v8A[k], 8, 64);                                 \
        v8A[k] += __shfl_xor(v8A[k], 16, 64);                                 \
        v8A[k] += __shfl_xor(v8A[k], 32, 64);                                 \
        v8B[k] += __shfl_xor(v8B[k], 8, 64);                                 \
        v8B[k] += __shfl_xor(v8B[k], 16, 64);                                 \
        v8B[k] += __shfl_xor(v8B[k], 32, 64);                                 \
    }

__global__ __launch_bounds__(256) void k_agg_relu(
        const unsigned* __restrict__ Hs, const float* __restrict__ dinv,
        const int* __restrict__ rowStart, const int* __restrict__ srcList,
        const float* __restrict__ bias, unsigned* __restrict__ O, int N) {
    int wid  = (blockIdx.x * blockDim.x + threadIdx.x) >> 6;
    int lane = threadIdx.x & 63;
    int i0 = 2 * wid;
    if (i0 >= N) return;
    i0 = __builtin_amdgcn_readfirstlane(i0);
    int i1 = (i0 + 1 < N) ? i0 + 1 : i0;
    int g = lane >> 3;   // edge slot 0..7
    int q = lane & 7;    // 16B slice of the row
    AGG_PAIR(Hs)
    if (g < 2) {
        int io = g ? i1 : i0;
        float u0 = g ? v8B[0] : v8A[0];
        float u1 = g ? v8B[1] : v8A[1];
        float u2 = g ? v8B[2] : v8A[2];
        float u3 = g ? v8B[3] : v8A[3];
        float u4 = g ? v8B[4] : v8A[4];
        float u5 = g ? v8B[5] : v8A[5];
        float u6 = g ? v8B[6] : v8A[6];
        float u7 = g ? v8B[7] : v8A[7];
        float di = dinv[io];
        float4 ba = *(const float4*)&bias[q * 8];
        float4 bb = *(const float4*)&bias[q * 8 + 4];
        const float* bp = (const float*)&ba;
        const float* bq = (const float*)&bb;
        float r0 = fmaxf(di * u0 + bp[0], 0.f);
        float r1 = fmaxf(di * u1 + bp[1], 0.f);
        float r2 = fmaxf(di * u2 + bp[2], 0.f);
        float r3 = fmaxf(di * u3 + bp[3], 0.f);
        float r4 = fmaxf(di * u4 + bq[0], 0.f);
        float r5 = fmaxf(di * u5 + bq[1], 0.f);
        float r6 = fmaxf(di * u6 + bq[2], 0.f);
        float r7 = fmaxf(di * u7 + bq[3], 0.f);
        uint4 o;
        o.x = cvtpk(r0, r1);
        o.y = cvtpk(r2, r3);
        o.z = cvtpk(r4, r5);
        o.w = cvtpk(r6, r7);
        *(uint4*)(O + (size_t)io * 32 + q * 4) = o;
    }
}

__global__ __launch_bounds__(256) void k_agg_fc(
        const unsigned* __restrict__ Hs, const float* __restrict__ dinv,
        const int* __restrict__ rowStart, const int* __restrict__ srcList,
        const float* __restrict__ b2, const float* __restrict__ Wfc,
        const float* __restrict__ bfc, float* __restrict__ out, int N) {
    int wid  = (blockIdx.x * blockDim.x + threadIdx.x) >> 6;
    int lane = threadIdx.x & 63;
    int i0 = 2 * wid;
    if (i0 >= N) return;
    i0 = __builtin_amdgcn_readfirstlane(i0);
    int i1 = (i0 + 1 < N) ? i0 + 1 : i0;
    int g = lane >> 3;
    int q = lane & 7;
    AGG_PAIR(Hs)
    if (g < 2) {
        int io = g ? i1 : i0;
        float u0 = g ? v8B[0] : v8A[0];
        float u1 = g ? v8B[1] : v8A[1];
        float u2 = g ? v8B[2] : v8A[2];
        float u3 = g ? v8B[3] : v8A[3];
        float u4 = g ? v8B[4] : v8A[4];
        float u5 = g ? v8B[5] : v8A[5];
        float u6 = g ? v8B[6] : v8A[6];
        float u7 = g ? v8B[7] : v8A[7];
        float di = dinv[io];
        float4 ba = *(const float4*)&b2[q * 8];
        float4 bb = *(const float4*)&b2[q * 8 + 4];
        float4 wa = *(const float4*)&Wfc[q * 8];
        float4 wb = *(const float4*)&Wfc[q * 8 + 4];
        const float* bp = (const float*)&ba;
        const float* bq = (const float*)&bb;
        const float* wp = (const float*)&wa;
        const float* wq = (const float*)&wb;
        float p = fmaxf(di * u0 + bp[0], 0.f) * wp[0]
                + fmaxf(di * u1 + bp[1], 0.f) * wp[1]
                + fmaxf(di * u2 + bp[2], 0.f) * wp[2]
                + fmaxf(di * u3 + bp[3], 0.f) * wp[3]
                + fmaxf(di * u4 + bq[0], 0.f) * wq[0]
                + fmaxf(di * u5 + bq[1], 0.f) * wq[1]
                + fmaxf(di * u6 + bq[2], 0.f) * wq[2]
                + fmaxf(di * u7 + bq[3], 0.f) * wq[3];
        p += __shfl_xor(p, 1, 64);
        p += __shfl_xor(p, 2, 64);
        p += __shfl_xor(p, 4, 64);
        if (q == 0) {
            float z = p + bfc[0];
            out[io] = 1.f / (1.f + __expf(-z));
        }
    }
}

// ---------------- host ----------------

extern "C" void kernel_launch(void* const* d_in, const int* in_sizes, int n_in,
                              void* d_out, int out_size, void* d_ws, size_t ws_size,
                              hipStream_t stream) {
    const float* x   = (const float*)d_in[0];
    const int*   ei  = (const int*)d_in[1];
    const float* W1  = (const float*)d_in[2];
    const float* b1  = (const float*)d_in[3];
    const float* W2  = (const float*)d_in[4];
    const float* b2  = (const float*)d_in[5];
    const float* Wfc = (const float*)d_in[6];
    const float* bfc = (const float*)d_in[7];
    float* out = (float*)d_out;

    int N  = in_sizes[0] / INDIM;   // 100000
    int E  = in_sizes[1] / 2;       // 3200000
    int EV = E + N;
    const int* srcA = ei;
    const int* dstA = ei + E;

    int NBUCK = (N + BNODES - 1) / BNODES;          // 1563 (<= MAXBUCK)
    size_t bucketBytes = (size_t)NBUCK * BCAP * 4;  // ~25.6 MB
    size_t hsBytes     = (size_t)(N + 1) * HIDD * 2; // bf16, +1 zero row

    char* ws = (char*)d_ws;
    size_t off = 0;
    auto alloc = [&](size_t bytes) -> char* {
        char* p = ws + off;
        off = (off + bytes + 255) & ~(size_t)255;
        return p;
    };
    int*   rowStart = (int*)alloc((size_t)(N + 9) * 4);   // +pad for pair reads
    float* dinv     = (float*)alloc((size_t)N * 4);
    int*   bcnt     = (int*)alloc((size_t)NBUCK * 4);
    int*   bstart   = (int*)alloc((size_t)NBUCK * 4);
    int*   srcList  = (int*)alloc((size_t)(EV + 48) * 4); // +48 pad for window loads
    char*  region   = alloc(bucketBytes > hsBytes ? bucketBytes : hsBytes);
    unsigned*       bucketBuf = (unsigned*)region;        // aliased with Hs
    unsigned short* Hs        = (unsigned short*)region;  // bf16 [N+1][64]
    unsigned* bufB = (unsigned*)alloc(hsBytes);           // bf16 [N+1][64] relu(agg1)

    hipMemsetAsync(bcnt, 0, (size_t)NBUCK * 4, stream);
    int aBlocks = (EV + CHUNK - 1) / CHUNK;  // 403
    hipLaunchKernelGGL(k_bucketA, dim3(aBlocks), dim3(ATHREADS), 0, stream,
                       srcA, dstA, bcnt, bucketBuf, E, N, NBUCK);
    hipLaunchKernelGGL(k_scanbuck, dim3(1), dim3(512), 0, stream,
                       bcnt, bstart, rowStart + N, NBUCK);
    hipLaunchKernelGGL(k_fillB, dim3(NBUCK), dim3(FB_THREADS), 0, stream,
                       bcnt, bucketBuf, bstart, rowStart, dinv, srcList, N);

    int gBlocks = (N + 63) / 64;  // 1563
    hipLaunchKernelGGL((k_gemm_mfma<INDIM, true>), dim3(gBlocks), dim3(256), 0, stream,
                       (const void*)x, W1, dinv, Hs, N);

    int aggWaves  = (N + 1) / 2;               // two nodes per wave
    int aggBlocks = (aggWaves + 3) / 4;        // 4 waves per block
    hipLaunchKernelGGL(k_agg_relu, dim3(aggBlocks), dim3(256), 0, stream,
                       (const unsigned*)Hs, dinv, rowStart, srcList, b1, bufB, N);

    hipLaunchKernelGGL((k_gemm_mfma<HIDD, false>), dim3(gBlocks), dim3(256), 0, stream,
                       (const void*)bufB, W2, dinv, Hs, N);

    hipLaunchKernelGGL(k_agg_fc, dim3(aggBlocks), dim3(256), 0, stream,
                       (const unsigned*)Hs, dinv, rowStart, srcList, b2, Wfc, bfc, out, N);
}

// Round 11
// 173.908 us; speedup vs baseline: 1.1937x; 1.0121x over previous
//
#include <hip/hip_runtime.h>

#define INDIM 128
#define HIDD 64
#define BSHIFT 6                 // 64 nodes per bucket
#define BNODES 64
#define BCAP 4096                // per-bucket capacity (mean fill ~2112)
#define MAXBUCK 2048             // bucket-array capacity (N<=131072)
#define CHUNK 8192               // edges per block in pass A (403 blocks)
#define ATHREADS 1024            // 16 waves/block
#define BPT (MAXBUCK / ATHREADS) // 2
#define FB_THREADS 512
#define FB_WAVES (FB_THREADS / 64)

typedef float f32x2 __attribute__((ext_vector_type(2)));
using short8 = __attribute__((ext_vector_type(8))) short;   // 8 bf16 (4 VGPRs)
using f32x4  = __attribute__((ext_vector_type(4))) float;   // MFMA acc

__device__ inline unsigned short f2bf(float f) {   // RNE f32->bf16
    unsigned u = __float_as_uint(f);
    return (unsigned short)((u + 0x7fff + ((u >> 16) & 1)) >> 16);
}
__device__ inline float bflo(unsigned v) { return __uint_as_float(v << 16); }
__device__ inline unsigned cvtpk(float a, float b) {  // {bf16(a), bf16(b)<<16} RNE
    unsigned r;
    asm("v_cvt_pk_bf16_f32 %0, %1, %2" : "=v"(r) : "v"(a), "v"(b));
    return r;
}

// ---------------- CSR build ----------------

// Pass A: per-block LDS counting sort of CHUNK edges by destination bucket.
// Round-8/10 memory structure kept EXACTLY (dLds cache of dstA; CHUNK=8192 so
// grid=403 > 256 CUs; no nontemporal hints -- round-7/9 lessons: nt on the
// scattered phase-4 read, or dropping dLds, each cost 2-3x HBM over-fetch).
__global__ __launch_bounds__(ATHREADS, 8) void k_bucketA(
        const int* __restrict__ srcA, const int* __restrict__ dstA,
        int* __restrict__ bcnt, unsigned* __restrict__ bucketBuf,
        int E, int N, int NBUCK) {
    __shared__ int cnt[MAXBUCK];              // 8 KB
    __shared__ int cur[MAXBUCK];              // 8 KB
    __shared__ unsigned short gbase[MAXBUCK]; // 4 KB
    __shared__ unsigned short stage[CHUNK];   // 16 KB (local edge offsets)
    __shared__ int dLds[CHUNK];               // 32 KB (cached destinations)
    __shared__ int wsum[ATHREADS / 64];
    int t = threadIdx.x;
    int EV = E + N;
    int begin = blockIdx.x * CHUNK;
    int end = begin + CHUNK;
    if (end > EV) end = EV;
    if (begin >= EV) return;
    int nLoc = end - begin;

    for (int b = t; b < MAXBUCK; b += ATHREADS) cnt[b] = 0;
    __syncthreads();

    // phase 1: single global read of dstA; histogram + cache d in LDS
    for (int i = begin + t; i < end; i += ATHREADS) {
        int d = (i < E) ? dstA[i] : (i - E);
        dLds[i - begin] = d;
        atomicAdd(&cnt[d >> BSHIFT], 1);
    }
    __syncthreads();

    // phase 2a: exclusive scan of cnt via wave shuffles
    int vq[BPT];
    int psum = 0;
#pragma unroll
    for (int q = 0; q < BPT; ++q) { vq[q] = cnt[t * BPT + q]; psum += vq[q]; }
    int lane = t & 63, w = t >> 6;
    int s = psum;
#pragma unroll
    for (int off = 1; off < 64; off <<= 1) {
        int u = __shfl_up(s, off, 64);
        if (lane >= off) s += u;
    }
    if (lane == 63) wsum[w] = s;
    __syncthreads();
    if (t < ATHREADS / 64) {
        int x = wsum[t];
#pragma unroll
        for (int off = 1; off < ATHREADS / 64; off <<= 1) {
            int u = __shfl_up(x, off, 64);
            if (t >= off) x += u;
        }
        wsum[t] = x;   // inclusive wave sums
    }
    __syncthreads();
    int run = ((w > 0) ? wsum[w - 1] : 0) + s - psum;
#pragma unroll
    for (int q = 0; q < BPT; ++q) {
        cur[t * BPT + q] = run;
        run += vq[q];
    }

    // phase 2b: reserve global runs (staggered sweep start per block)
    int b0 = (int)(((unsigned)blockIdx.x * 683u) % (unsigned)NBUCK);
    for (int idx = t; idx < NBUCK; idx += ATHREADS) {
        int b = idx + b0;
        if (b >= NBUCK) b -= NBUCK;
        int c = cnt[b];
        gbase[b] = (unsigned short)((c > 0) ? atomicAdd(&bcnt[b], c) : 0);
    }
    __syncthreads();

    // phase 3: counting-sort local edge offsets (LDS-only)
    for (int j = t; j < nLoc; j += ATHREADS) {
        int d = dLds[j];
        int slot = atomicAdd(&cur[d >> BSHIFT], 1);
        stage[slot] = (unsigned short)j;
    }
    __syncthreads();

    // phase 4: linear write-out; d from LDS, only srcA read from global
    for (int j = t; j < nLoc; j += ATHREADS) {
        int loc = (int)stage[j];
        int d = dLds[loc];
        int i2 = begin + loc;
        int s2 = (i2 < E) ? srcA[i2] : d;   // self-loop: s == d
        int b = d >> BSHIFT;
        int local = j - (cur[b] - cnt[b]);  // cur[b] = start+cnt after phase 3
        int slot = (int)gbase[b] + local;
        if (slot < BCAP)
            bucketBuf[(size_t)b * BCAP + slot] = ((unsigned)s2 << BSHIFT) | (d & (BNODES - 1));
    }
}

// Pass B: per-bucket counting sort by node. Round-11: the bucket-prefix scan
// (former k_scanbuck launch) is folded in -- each block computes its own
// base = sum(bcnt[0..b-1]) from the L2-hot 6 KB bcnt array (3 grid-stride
// loads + block reduce), killing one dispatch + its launch gap. Wave-private
// histograms + scatter cursors (8x less LDS atomic contention; per-node sums
// are order-free). Wave 0 does the 64-wide scan and per-wave sub-run bases.
// Last block writes rowStart[N] = total (= E + N).
__global__ __launch_bounds__(FB_THREADS) void k_fillB(
        const int* __restrict__ bcnt, const unsigned* __restrict__ bucketBuf,
        int* __restrict__ rowStart,
        float* __restrict__ dinv, int* __restrict__ srcList, int N, int NBUCK) {
    __shared__ int cntw[FB_WAVES][BNODES];   // 2 KB
    __shared__ int curw[FB_WAVES][BNODES];   // 2 KB
    __shared__ unsigned stage[BCAP];         // 16 KB
    __shared__ int redw[FB_WAVES];
    int b = blockIdx.x;
    int t = threadIdx.x;
    int w = t >> 6, lane = t & 63;
    cntw[w][lane] = 0;
    // base = exclusive prefix sum of bcnt up to b (bcnt is tiny & L2-hot)
    int part = 0;
    for (int i = t; i < b; i += FB_THREADS) part += bcnt[i];
#pragma unroll
    for (int off = 32; off; off >>= 1) part += __shfl_xor(part, off, 64);
    if (lane == 0) redw[w] = part;
    __syncthreads();
    int base = 0;
#pragma unroll
    for (int ww = 0; ww < FB_WAVES; ++ww) base += redw[ww];

    int n = bcnt[b];
    if (n > BCAP) n = BCAP;
    if (b == NBUCK - 1 && t == 0) rowStart[N] = base + n;  // total = E + N
    const unsigned* buf = bucketBuf + (size_t)b * BCAP;
    for (int e = t; e < n; e += FB_THREADS)
        atomicAdd(&cntw[w][buf[e] & (BNODES - 1)], 1);
    __syncthreads();
    if (w == 0) {
        // lane == node id within bucket
        int tot = 0;
        int pre[FB_WAVES];
#pragma unroll
        for (int ww = 0; ww < FB_WAVES; ++ww) { pre[ww] = tot; tot += cntw[ww][lane]; }
        int s = tot;
#pragma unroll
        for (int off = 1; off < BNODES; off <<= 1) {
            int u = __shfl_up(s, off, 64);
            if (lane >= off) s += u;
        }
        int excl = s - tot;
        int node = b * BNODES + lane;
        if (node < N) {
            rowStart[node] = base + excl;
            dinv[node] = rsqrtf((float)tot);   // tot >= 1 (self-loop)
        }
#pragma unroll
        for (int ww = 0; ww < FB_WAVES; ++ww) curw[ww][lane] = excl + pre[ww];
    }
    __syncthreads();
    for (int e = t; e < n; e += FB_THREADS) {
        unsigned entry = buf[e];
        int slot = atomicAdd(&curw[w][entry & (BNODES - 1)], 1);
        stage[slot] = entry;
    }
    __syncthreads();
    for (int j = t; j < n; j += FB_THREADS)
        srcList[base + j] = (int)(stage[j] >> BSHIFT);
}

// ---------- MFMA GEMM: Hs = bf16((X@W)*dinv), 64x64 tile, K-blocked by 64 ----------
// Error-compensated bf16 splits: F32IN: X=Xh+Xl, W=Wh+Wl, D = Xh*Wh + Xh*Wl + Xl*Wh
// (drops Xl*Wl <= 2^-16 rel). !F32IN: X exact bf16, D = X*Wh + X*Wl.
// A/B fragment packing uses k = 8*(lane>>4)+j for BOTH operands. C/D layout is
// HW-fixed: row = 4*(lane>>4)+reg, col = lane&15 (verified round 4).
template <int K, bool F32IN>
__global__ __launch_bounds__(256) void k_gemm_mfma(const void* __restrict__ Xv,
                                                   const float* __restrict__ W,
                                                   const float* __restrict__ dinv,
                                                   unsigned short* __restrict__ Hs,
                                                   int N) {
    __shared__ unsigned short AH[64][72];
    __shared__ unsigned short AL[64][72];
    __shared__ unsigned short BH[64][72];
    __shared__ unsigned short BL[64][72];
    int t = threadIdx.x;
    int row0 = blockIdx.x * 64;
    if (F32IN && blockIdx.x == 0 && t < 32)   // zero row N of Hs (agg mask target)
        ((unsigned*)Hs)[(size_t)N * 32 + t] = 0u;
    int w = t >> 6, lane = t & 63;
    int lr = lane & 15, lh = lane >> 4;
    f32x4 acc[4];
#pragma unroll
    for (int tn = 0; tn < 4; ++tn) acc[tn] = (f32x4){0.f, 0.f, 0.f, 0.f};

    for (int kb = 0; kb < K; kb += 64) {
        if (kb) __syncthreads();
        // ---- stage A tile (rows row0..+63, k-cols kb..kb+63) ----
        if constexpr (F32IN) {
            const float* X = (const float*)Xv;
#pragma unroll
            for (int qq = 0; qq < 4; ++qq) {
                int f = qq * 256 + t;
                int r = f >> 4, c4 = (f & 15) << 2;
                int row = row0 + r;
                float4 x = make_float4(0.f, 0.f, 0.f, 0.f);
                if (row < N) x = *(const float4*)&X[(size_t)row * K + kb + c4];
                unsigned u01 = cvtpk(x.x, x.y), u23 = cvtpk(x.z, x.w);
                float l0 = x.x - bflo(u01);
                float l1 = x.y - __uint_as_float(u01 & 0xffff0000u);
                float l2 = x.z - bflo(u23);
                float l3 = x.w - __uint_as_float(u23 & 0xffff0000u);
                unsigned v01 = cvtpk(l0, l1), v23 = cvtpk(l2, l3);
                *(uint2*)&AH[r][c4] = make_uint2(u01, u23);
                *(uint2*)&AL[r][c4] = make_uint2(v01, v23);
            }
        } else {
            const unsigned* X = (const unsigned*)Xv;   // bf16 pairs [N][32]
#pragma unroll
            for (int qq = 0; qq < 2; ++qq) {
                int f = qq * 256 + t;
                int r = f >> 3, c8 = (f & 7) << 3;
                int row = row0 + r;
                uint4 v = make_uint4(0u, 0u, 0u, 0u);
                if (row < N) v = *(const uint4*)&X[(size_t)row * 32 + (c8 >> 1)];
                *(uint4*)&AH[r][c8] = v;
            }
        }
        // ---- stage B = W^T slice (k rows kb..kb+63, all 64 n), hi/lo ----
        {
            int n = (t & 15) + ((t >> 6) << 4);
            int kc0 = ((t >> 4) & 3) << 2;
#pragma unroll
            for (int qq = 0; qq < 4; ++qq) {
                int kc = kc0 + (qq << 4);
                float w0 = W[(size_t)(kb + kc + 0) * HIDD + n];
                float w1 = W[(size_t)(kb + kc + 1) * HIDD + n];
                float w2 = W[(size_t)(kb + kc + 2) * HIDD + n];
                float w3 = W[(size_t)(kb + kc + 3) * HIDD + n];
                unsigned u01 = cvtpk(w0, w1), u23 = cvtpk(w2, w3);
                float l0 = w0 - bflo(u01);
                float l1 = w1 - __uint_as_float(u01 & 0xffff0000u);
                float l2 = w2 - bflo(u23);
                float l3 = w3 - __uint_as_float(u23 & 0xffff0000u);
                unsigned v01 = cvtpk(l0, l1), v23 = cvtpk(l2, l3);
                *(uint2*)&BH[n][kc] = make_uint2(u01, u23);
                *(uint2*)&BL[n][kc] = make_uint2(v01, v23);
            }
        }
        __syncthreads();
        // ---- fragments + MFMA ----
#pragma unroll
        for (int s = 0; s < 2; ++s) {
            short8 ah = *(const short8*)&AH[16 * w + lr][32 * s + 8 * lh];
#pragma unroll
            for (int tn = 0; tn < 4; ++tn) {
                short8 bh = *(const short8*)&BH[16 * tn + lr][32 * s + 8 * lh];
                short8 bl = *(const short8*)&BL[16 * tn + lr][32 * s + 8 * lh];
                acc[tn] = __builtin_amdgcn_mfma_f32_16x16x32_bf16(ah, bh, acc[tn], 0, 0, 0);
                acc[tn] = __builtin_amdgcn_mfma_f32_16x16x32_bf16(ah, bl, acc[tn], 0, 0, 0);
                if constexpr (F32IN) {
                    short8 al = *(const short8*)&AL[16 * w + lr][32 * s + 8 * lh];
                    acc[tn] = __builtin_amdgcn_mfma_f32_16x16x32_bf16(al, bh, acc[tn], 0, 0, 0);
                }
            }
        }
    }
    // ---- epilogue: D row = 4*lh + r, col = 16*tn + lr ----
    int rb = row0 + 16 * w + 4 * lh;
#pragma unroll
    for (int r = 0; r < 4; ++r) {
        int row = rb + r;
        if (row < N) {
            float di = dinv[row];
#pragma unroll
            for (int tn = 0; tn < 4; ++tn)
                Hs[(size_t)row * HIDD + 16 * tn + lr] = f2bf(acc[tn][r] * di);
        }
    }
}

// ---------- aggregation: wave per TWO nodes; 8 edge slots x 8 lanes (16B/lane).
// Round-5 structure (measured best): fixed straight-line 48-edge masked window
// per node, all 12 gathers issued back-to-back. Masked slots redirect to the
// L1-hot zero row N. Rare degree>48 drained by unmasked 32-edge pre-loops.
// Accumulate: per uint PAIR one v_pk_add_f32 eats raw hi-bf16 halves (garbage
// <= 2^-8 rel), one eats shifted lo halves: 8 VALU / uint4.

#define PK2(accH, accL, u0, u1)                                              \
    do {                                                                     \
        f32x2 hh_, ll_;                                                      \
        hh_.x = __uint_as_float(u0);                                         \
        hh_.y = __uint_as_float(u1);                                         \
        ll_.x = __uint_as_float((u0) << 16);                                 \
        ll_.y = __uint_as_float((u1) << 16);                                 \
        asm("v_pk_add_f32 %0, %1, %0" : "+v"(accH) : "v"(hh_));              \
        asm("v_pk_add_f32 %0, %1, %0" : "+v"(accL) : "v"(ll_));              \
    } while (0)

#define ACC4(H0, L0, H1, L1, v4)                                             \
    do { PK2(H0, L0, (v4).x, (v4).y); PK2(H1, L1, (v4).z, (v4).w); } while (0)

#define ROWG(sidx) (*(const uint4*)(Hb + (((unsigned)(sidx) << 7) + qb)))

#define SRC6(P, ebeg, eend)                                                  \
    int P##b = (ebeg) + g;                                                   \
    int P##s0 = (P##b      < (eend)) ? srcList[P##b]      : N;               \
    int P##s1 = (P##b + 8  < (eend)) ? srcList[P##b + 8]  : N;               \
    int P##s2 = (P##b + 16 < (eend)) ? srcList[P##b + 16] : N;               \
    int P##s3 = (P##b + 24 < (eend)) ? srcList[P##b + 24] : N;               \
    int P##s4 = (P##b + 32 < (eend)) ? srcList[P##b + 32] : N;               \
    int P##s5 = (P##b + 40 < (eend)) ? srcList[P##b + 40] : N

#define GATH6(P)                                                             \
    uint4 P##v0 = ROWG(P##s0); uint4 P##v1 = ROWG(P##s1);                    \
    uint4 P##v2 = ROWG(P##s2); uint4 P##v3 = ROWG(P##s3);                    \
    uint4 P##v4 = ROWG(P##s4); uint4 P##v5 = ROWG(P##s5)

#define ACC6(P, H0, L0, H1, L1)                                              \
    do { ACC4(H0, L0, H1, L1, P##v0); ACC4(H0, L0, H1, L1, P##v1);           \
         ACC4(H0, L0, H1, L1, P##v2); ACC4(H0, L0, H1, L1, P##v3);           \
         ACC4(H0, L0, H1, L1, P##v4); ACC4(H0, L0, H1, L1, P##v5); } while (0)

#define BIGLOOP(ePos, eEnd, H0, L0, H1, L1)                                  \
    while ((eEnd) - (ePos) > 48) {  /* rare: degree > 48 */                  \
        int s0 = srcList[(ePos) + g];                                        \
        int s1 = srcList[(ePos) + 8 + g];                                    \
        int s2 = srcList[(ePos) + 16 + g];                                   \
        int s3 = srcList[(ePos) + 24 + g];                                   \
        uint4 v0 = ROWG(s0); uint4 v1 = ROWG(s1);                            \
        uint4 v2 = ROWG(s2); uint4 v3 = ROWG(s3);                            \
        ACC4(H0, L0, H1, L1, v0); ACC4(H0, L0, H1, L1, v1);                  \
        ACC4(H0, L0, H1, L1, v2); ACC4(H0, L0, H1, L1, v3);                  \
        (ePos) += 32;                                                        \
    }

// shared pair body: accumulates nodes i0,i1 into v8A/v8B (reduced across wave)
#define AGG_PAIR(HPTR)                                                       \
    const char* Hb = (const char*)(HPTR);                                    \
    unsigned qb = (unsigned)q << 4;                                          \
    int2 ra = *(const int2*)&rowStart[i0];                                   \
    int rc = rowStart[i0 + 2];                                               \
    int beg0 = ra.x, end0 = ra.y;                                            \
    int beg1 = (i1 == i0) ? ra.x : ra.y;                                     \
    int end1 = (i1 == i0) ? ra.y : rc;                                       \
    f32x2 h0A = {0.f,0.f}, l0A = {0.f,0.f}, h1A = {0.f,0.f}, l1A = {0.f,0.f};\
    f32x2 h0B = {0.f,0.f}, l0B = {0.f,0.f}, h1B = {0.f,0.f}, l1B = {0.f,0.f};\
    int e0 = beg0, e1 = beg1;                                                \
    BIGLOOP(e0, end0, h0A, l0A, h1A, l1A)                                    \
    BIGLOOP(e1, end1, h0B, l0B, h1B, l1B)                                    \
    SRC6(A, e0, end0);                                                       \
    SRC6(B, e1, end1);                                                       \
    GATH6(A);                                                                \
    GATH6(B);                                                                \
    ACC6(A, h0A, l0A, h1A, l1A);                                             \
    ACC6(B, h0B, l0B, h1B, l1B);                                             \
    float v8A[8] = {l0A.x, h0A.x, l0A.y, h0A.y, l1A.x, h1A.x, l1A.y, h1A.y}; \
    float v8B[8] = {l0B.x, h0B.x, l0B.y, h0B.y, l1B.x, h1B.x, l1B.y, h1B.y}; \
    _Pragma("unroll")                                                        \
    for (int k = 0; k < 8; ++k) {                                            \
        v8A[k] += __shfl_xor(v8A[k], 8, 64);                                 \
        v8A[k] += __shfl_xor(v8A[k], 16, 64);                                 \
        v8A[k] += __shfl_xor(v8A[k], 32, 64);                                 \
        v8B[k] += __shfl_xor(v8B[k], 8, 64);                                 \
        v8B[k] += __shfl_xor(v8B[k], 16, 64);                                 \
        v8B[k] += __shfl_xor(v8B[k], 32, 64);                                 \
    }

__global__ __launch_bounds__(256) void k_agg_relu(
        const unsigned* __restrict__ Hs, const float* __restrict__ dinv,
        const int* __restrict__ rowStart, const int* __restrict__ srcList,
        const float* __restrict__ bias, unsigned* __restrict__ O, int N) {
    int wid  = (blockIdx.x * blockDim.x + threadIdx.x) >> 6;
    int lane = threadIdx.x & 63;
    int i0 = 2 * wid;
    if (i0 >= N) return;
    i0 = __builtin_amdgcn_readfirstlane(i0);
    int i1 = (i0 + 1 < N) ? i0 + 1 : i0;
    int g = lane >> 3;   // edge slot 0..7
    int q = lane & 7;    // 16B slice of the row
    AGG_PAIR(Hs)
    if (g < 2) {
        int io = g ? i1 : i0;
        float u0 = g ? v8B[0] : v8A[0];
        float u1 = g ? v8B[1] : v8A[1];
        float u2 = g ? v8B[2] : v8A[2];
        float u3 = g ? v8B[3] : v8A[3];
        float u4 = g ? v8B[4] : v8A[4];
        float u5 = g ? v8B[5] : v8A[5];
        float u6 = g ? v8B[6] : v8A[6];
        float u7 = g ? v8B[7] : v8A[7];
        float di = dinv[io];
        float4 ba = *(const float4*)&bias[q * 8];
        float4 bb = *(const float4*)&bias[q * 8 + 4];
        const float* bp = (const float*)&ba;
        const float* bq = (const float*)&bb;
        float r0 = fmaxf(di * u0 + bp[0], 0.f);
        float r1 = fmaxf(di * u1 + bp[1], 0.f);
        float r2 = fmaxf(di * u2 + bp[2], 0.f);
        float r3 = fmaxf(di * u3 + bp[3], 0.f);
        float r4 = fmaxf(di * u4 + bq[0], 0.f);
        float r5 = fmaxf(di * u5 + bq[1], 0.f);
        float r6 = fmaxf(di * u6 + bq[2], 0.f);
        float r7 = fmaxf(di * u7 + bq[3], 0.f);
        uint4 o;
        o.x = cvtpk(r0, r1);
        o.y = cvtpk(r2, r3);
        o.z = cvtpk(r4, r5);
        o.w = cvtpk(r6, r7);
        *(uint4*)(O + (size_t)io * 32 + q * 4) = o;
    }
}

__global__ __launch_bounds__(256) void k_agg_fc(
        const unsigned* __restrict__ Hs, const float* __restrict__ dinv,
        const int* __restrict__ rowStart, const int* __restrict__ srcList,
        const float* __restrict__ b2, const float* __restrict__ Wfc,
        const float* __restrict__ bfc, float* __restrict__ out, int N) {
    int wid  = (blockIdx.x * blockDim.x + threadIdx.x) >> 6;
    int lane = threadIdx.x & 63;
    int i0 = 2 * wid;
    if (i0 >= N) return;
    i0 = __builtin_amdgcn_readfirstlane(i0);
    int i1 = (i0 + 1 < N) ? i0 + 1 : i0;
    int g = lane >> 3;
    int q = lane & 7;
    AGG_PAIR(Hs)
    if (g < 2) {
        int io = g ? i1 : i0;
        float u0 = g ? v8B[0] : v8A[0];
        float u1 = g ? v8B[1] : v8A[1];
        float u2 = g ? v8B[2] : v8A[2];
        float u3 = g ? v8B[3] : v8A[3];
        float u4 = g ? v8B[4] : v8A[4];
        float u5 = g ? v8B[5] : v8A[5];
        float u6 = g ? v8B[6] : v8A[6];
        float u7 = g ? v8B[7] : v8A[7];
        float di = dinv[io];
        float4 ba = *(const float4*)&b2[q * 8];
        float4 bb = *(const float4*)&b2[q * 8 + 4];
        float4 wa = *(const float4*)&Wfc[q * 8];
        float4 wb = *(const float4*)&Wfc[q * 8 + 4];
        const float* bp = (const float*)&ba;
        const float* bq = (const float*)&bb;
        const float* wp = (const float*)&wa;
        const float* wq = (const float*)&wb;
        float p = fmaxf(di * u0 + bp[0], 0.f) * wp[0]
                + fmaxf(di * u1 + bp[1], 0.f) * wp[1]
                + fmaxf(di * u2 + bp[2], 0.f) * wp[2]
                + fmaxf(di * u3 + bp[3], 0.f) * wp[3]
                + fmaxf(di * u4 + bq[0], 0.f) * wq[0]
                + fmaxf(di * u5 + bq[1], 0.f) * wq[1]
                + fmaxf(di * u6 + bq[2], 0.f) * wq[2]
                + fmaxf(di * u7 + bq[3], 0.f) * wq[3];
        p += __shfl_xor(p, 1, 64);
        p += __shfl_xor(p, 2, 64);
        p += __shfl_xor(p, 4, 64);
        if (q == 0) {
            float z = p + bfc[0];
            out[io] = 1.f / (1.f + __expf(-z));
        }
    }
}

// ---------------- host ----------------

extern "C" void kernel_launch(void* const* d_in, const int* in_sizes, int n_in,
                              void* d_out, int out_size, void* d_ws, size_t ws_size,
                              hipStream_t stream) {
    const float* x   = (const float*)d_in[0];
    const int*   ei  = (const int*)d_in[1];
    const float* W1  = (const float*)d_in[2];
    const float* b1  = (const float*)d_in[3];
    const float* W2  = (const float*)d_in[4];
    const float* b2  = (const float*)d_in[5];
    const float* Wfc = (const float*)d_in[6];
    const float* bfc = (const float*)d_in[7];
    float* out = (float*)d_out;

    int N  = in_sizes[0] / INDIM;   // 100000
    int E  = in_sizes[1] / 2;       // 3200000
    int EV = E + N;
    const int* srcA = ei;
    const int* dstA = ei + E;

    int NBUCK = (N + BNODES - 1) / BNODES;          // 1563 (<= MAXBUCK)
    size_t bucketBytes = (size_t)NBUCK * BCAP * 4;  // ~25.6 MB
    size_t hsBytes     = (size_t)(N + 1) * HIDD * 2; // bf16, +1 zero row

    char* ws = (char*)d_ws;
    size_t off = 0;
    auto alloc = [&](size_t bytes) -> char* {
        char* p = ws + off;
        off = (off + bytes + 255) & ~(size_t)255;
        return p;
    };
    int*   rowStart = (int*)alloc((size_t)(N + 9) * 4);   // +pad for pair reads
    float* dinv     = (float*)alloc((size_t)N * 4);
    int*   bcnt     = (int*)alloc((size_t)NBUCK * 4);
    int*   srcList  = (int*)alloc((size_t)(EV + 48) * 4); // +48 pad for window loads
    char*  region   = alloc(bucketBytes > hsBytes ? bucketBytes : hsBytes);
    unsigned*       bucketBuf = (unsigned*)region;        // aliased with Hs
    unsigned short* Hs        = (unsigned short*)region;  // bf16 [N+1][64]
    unsigned* bufB = (unsigned*)alloc(hsBytes);           // bf16 [N+1][64] relu(agg1)

    hipMemsetAsync(bcnt, 0, (size_t)NBUCK * 4, stream);
    int aBlocks = (EV + CHUNK - 1) / CHUNK;  // 403
    hipLaunchKernelGGL(k_bucketA, dim3(aBlocks), dim3(ATHREADS), 0, stream,
                       srcA, dstA, bcnt, bucketBuf, E, N, NBUCK);
    hipLaunchKernelGGL(k_fillB, dim3(NBUCK), dim3(FB_THREADS), 0, stream,
                       bcnt, bucketBuf, rowStart, dinv, srcList, N, NBUCK);

    int gBlocks = (N + 63) / 64;  // 1563
    hipLaunchKernelGGL((k_gemm_mfma<INDIM, true>), dim3(gBlocks), dim3(256), 0, stream,
                       (const void*)x, W1, dinv, Hs, N);

    int aggWaves  = (N + 1) / 2;               // two nodes per wave
    int aggBlocks = (aggWaves + 3) / 4;        // 4 waves per block
    hipLaunchKernelGGL(k_agg_relu, dim3(aggBlocks), dim3(256), 0, stream,
                       (const unsigned*)Hs, dinv, rowStart, srcList, b1, bufB, N);

    hipLaunchKernelGGL((k_gemm_mfma<HIDD, false>), dim3(gBlocks), dim3(256), 0, stream,
                       (const void*)bufB, W2, dinv, Hs, N);

    hipLaunchKernelGGL(k_agg_fc, dim3(aggBlocks), dim3(256), 0, stream,
                       (const unsigned*)Hs, dinv, rowStart, srcList, b2, Wfc, bfc, out, N);
}